// Round 4
// baseline (604.948 us; speedup 1.0000x reference)
//
#include <hip/hip_runtime.h>
#include <hip/hip_bf16.h>

// MultiheadAttention (heads=1): B=4, N=4096, D=512, PROJ=512. scale=0.125.
// Inputs fp32, output fp32. Internal: bf16 MFMA, fp32 accum.
//
// R4 changes vs R3 (both occupancy levers):
//  - flash_attn: 1024 thr (16 waves, 4/SIMD), Tk=128 (halves barrier/key),
//    Q staged in LDS (VGPR<=128 so 16-wave block is resident), Sld aliases stage.
//  - gemm: 128x128 tile, BK=64, 4 waves x (64x64) acc, grid 512 blocks (2/CU).

typedef __attribute__((ext_vector_type(8))) short bf16x8;
typedef __attribute__((ext_vector_type(4))) float f32x4;

#define NB 4
#define NN 4096
#define ND 512

__device__ __forceinline__ f32x4 mfma16(bf16x8 a, bf16x8 b, f32x4 c) {
    return __builtin_amdgcn_mfma_f32_16x16x32_bf16(a, b, c, 0, 0, 0);
}
__device__ __forceinline__ short f2bf(float f) {
    __hip_bfloat16 h = __float2bfloat16(f);
    return *reinterpret_cast<short*>(&h);
}

// ---------------- weight transpose: Wt[c][r] (bf16) = W[r][c] (fp32), 512x512 ----
struct Ptrs4 {
    const float* in[4];
    short* out[4];
};

__global__ void transpose_w(Ptrs4 p) {
    __shared__ short tile[32][33];
    const float* in = p.in[blockIdx.z];
    short* out = p.out[blockIdx.z];
    int r0 = blockIdx.y * 32, c0 = blockIdx.x * 32;
    int tx = threadIdx.x, ty = threadIdx.y;  // 32 x 8
    for (int i = 0; i < 32; i += 8)
        tile[ty + i][tx] = f2bf(in[(r0 + ty + i) * 512 + c0 + tx]);
    __syncthreads();
    for (int i = 0; i < 32; i += 8)
        out[(c0 + ty + i) * 512 + r0 + tx] = tile[tx][ty + i];
}

// ---------------- bt-form GEMM + bias, 128x128 tile, BK=64 ----------------
// C[m][n] = sum_k A[m][k]*Bt[n][k] + bias[n].  K=512 fixed (8 kt steps).
// 256 threads / 4 waves; wave (wm=w&1, wn=w>>1) computes 64x64 = 4x4 MFMA tiles.
// AF32: A fp32 (cvt at staging). VT: write C^T per batch (for vpT). OF32: fp32 out.
template <int AF32, int VT, int OF32>
__global__ __launch_bounds__(256, 2) void gemm_bt_bias(
    const void* __restrict__ Av, const short* __restrict__ Bt,
    const float* __restrict__ bias, void* __restrict__ C) {
    __shared__ short As[128][72];
    __shared__ short Bs[128][72];
    int tid = threadIdx.x;
    int lane = tid & 63, w = tid >> 6;
    int l15 = lane & 15, l4 = lane >> 4;
    int wm = w & 1, wn = w >> 1;
    int m0 = blockIdx.y * 128, n0 = blockIdx.x * 128;
    f32x4 acc[4][4] = {};
    for (int kt = 0; kt < 512; kt += 64) {
        __syncthreads();
#pragma unroll
        for (int i = 0; i < 4; i++) {
            int vv = tid + i * 256;
            int row = vv >> 3, col8 = (vv & 7) * 8;
            if (AF32) {
                const float* A = (const float*)Av;
                const float* src = &A[(size_t)(m0 + row) * 512 + kt + col8];
                float4 f0 = *(const float4*)src;
                float4 f1 = *(const float4*)(src + 4);
                short tmp[8];
                tmp[0] = f2bf(f0.x); tmp[1] = f2bf(f0.y);
                tmp[2] = f2bf(f0.z); tmp[3] = f2bf(f0.w);
                tmp[4] = f2bf(f1.x); tmp[5] = f2bf(f1.y);
                tmp[6] = f2bf(f1.z); tmp[7] = f2bf(f1.w);
                *(bf16x8*)&As[row][col8] = *(bf16x8*)tmp;
            } else {
                const short* A = (const short*)Av;
                *(bf16x8*)&As[row][col8] = *(const bf16x8*)&A[(size_t)(m0 + row) * 512 + kt + col8];
            }
            *(bf16x8*)&Bs[row][col8] = *(const bf16x8*)&Bt[(size_t)(n0 + row) * 512 + kt + col8];
        }
        __syncthreads();
#pragma unroll
        for (int kb = 0; kb < 2; kb++) {
            int ko = kb * 32 + l4 * 8;
            bf16x8 af[4], bf[4];
#pragma unroll
            for (int t = 0; t < 4; t++) {
                af[t] = *(const bf16x8*)&As[wm * 64 + t * 16 + l15][ko];
                bf[t] = *(const bf16x8*)&Bs[wn * 64 + t * 16 + l15][ko];
            }
#pragma unroll
            for (int mt = 0; mt < 4; mt++)
#pragma unroll
                for (int nt = 0; nt < 4; nt++)
                    acc[mt][nt] = mfma16(af[mt], bf[nt], acc[mt][nt]);
        }
    }
#pragma unroll
    for (int mt = 0; mt < 4; mt++)
#pragma unroll
        for (int nt = 0; nt < 4; nt++) {
            f32x4 vv = acc[mt][nt];
            int col = n0 + wn * 64 + nt * 16 + l15;
            float bv = bias[col];
#pragma unroll
            for (int r = 0; r < 4; r++) {
                int row = m0 + wm * 64 + mt * 16 + l4 * 4 + r;
                float val = vv[r] + bv;
                if (VT) {
                    int b = row >> 12, j = row & 4095;
                    ((short*)C)[(size_t)b * (ND * NN) + (size_t)col * NN + j] = f2bf(val);
                } else if (OF32) {
                    ((float*)C)[(size_t)row * 512 + col] = val;
                } else {
                    ((short*)C)[(size_t)row * 512 + col] = f2bf(val);
                }
            }
        }
}

// ---------------- flash attention v2 ----------------
// Block: 64 Q-rows x one batch; 1024 threads (16 waves, 4/SIMD). Tk=128 keys/chunk.
// Wave (wr=w&3, wc=w>>2): S tile rows 16*wr, key-cols [wc*32, wc*32+32).
// O cols per wave: eh*256 + wc*64 + i*16, i<4 (128 e-cols). Q lives in LDS.
// LDS (154.4 KB): Qs[64][520] | stage{ Ks[128][264] / Vs[256][136] / Sld[64][132]f32 }
//                 | Pld[64][136] | mrow/lrow/arow[64].
__global__ __launch_bounds__(1024) void flash_attn(
    const short* __restrict__ qp, const short* __restrict__ kp,
    const short* __restrict__ vpT, short* __restrict__ dpa) {
    __shared__ __align__(16) char smem[154368];
    short* Qs   = (short*)smem;                    // 64*520 shorts = 66560 B
    short* stage = (short*)(smem + 66560);         // 69632 B (Ks/Vs), aliased by Sld
    float* Sld  = (float*)(smem + 66560);          // 64*132 fp32 = 33792 B
    short* Pld  = (short*)(smem + 136192);         // 64*136 shorts = 17408 B
    float* mrow = (float*)(smem + 153600);
    float* lrow = mrow + 64;
    float* arow = mrow + 128;

    int tid = threadIdx.x;
    int lane = tid & 63, w = tid >> 6;
    int l15 = lane & 15, l4 = lane >> 4;
    int wr = w & 3;    // S row block (16 rows)
    int wc = w >> 2;   // 0..3: key-col / e-col quarter
    int b = blockIdx.y;
    int q0 = blockIdx.x * 64;

    const short* qpb = qp + (size_t)b * (NN * ND);
    const short* kpb = kp + (size_t)b * (NN * ND);
    const short* vtb = vpT + (size_t)b * (ND * NN);

    // stage Q tile into LDS: 64 rows x 512 k
#pragma unroll
    for (int i = 0; i < 4; i++) {
        int vv = tid + i * 1024;
        int row = vv >> 6, col8 = (vv & 63) * 8;
        *(bf16x8*)&Qs[row * 520 + col8] = *(const bf16x8*)&qpb[(size_t)(q0 + row) * ND + col8];
    }
    f32x4 oacc[8] = {};
    if (tid < 64) { mrow[tid] = -1e30f; lrow[tid] = 0.f; }

    for (int j0 = 0; j0 < NN; j0 += 128) {
        // ---- S = Q K^T over 128 keys, two k-halves staged ----
        f32x4 sacc[2] = {};
#pragma unroll
        for (int kh = 0; kh < 2; kh++) {
            __syncthreads();   // stage free (prev readers done)
#pragma unroll
            for (int i = 0; i < 4; i++) {
                int vv = tid + i * 1024;
                int row = vv >> 5, col8 = (vv & 31) * 8;  // 128 x 256
                *(bf16x8*)&stage[row * 264 + col8] =
                    *(const bf16x8*)&kpb[(size_t)(j0 + row) * ND + kh * 256 + col8];
            }
            __syncthreads();
#pragma unroll
            for (int i = 0; i < 8; i++) {
                bf16x8 qf = *(const bf16x8*)&Qs[(wr * 16 + l15) * 520 + kh * 256 + i * 32 + l4 * 8];
#pragma unroll
                for (int c = 0; c < 2; c++) {
                    bf16x8 kf = *(const bf16x8*)&stage[(wc * 32 + c * 16 + l15) * 264 + i * 32 + l4 * 8];
                    sacc[c] = mfma16(qf, kf, sacc[c]);
                }
            }
        }
        __syncthreads();   // all QK reads of stage done -> Sld may overwrite it
#pragma unroll
        for (int c = 0; c < 2; c++)
#pragma unroll
            for (int r = 0; r < 4; r++)
                Sld[(wr * 16 + l4 * 4 + r) * 132 + wc * 32 + c * 16 + l15] = sacc[c][r] * 0.125f;
        __syncthreads();
        // ---- online softmax: 16 threads per row, 8 cols each (128 cols) ----
        {
            int row = tid >> 4, c4 = tid & 15;
            float v[8];
            float mx = -1e30f;
#pragma unroll
            for (int i = 0; i < 8; i++) { v[i] = Sld[row * 132 + c4 * 8 + i]; mx = fmaxf(mx, v[i]); }
#pragma unroll
            for (int off = 1; off < 16; off <<= 1) mx = fmaxf(mx, __shfl_xor(mx, off));
            float mo = mrow[row];
            float mn = fmaxf(mo, mx);
            float ps = 0.f;
#pragma unroll
            for (int i = 0; i < 8; i++) { v[i] = __expf(v[i] - mn); ps += v[i]; }
#pragma unroll
            for (int off = 1; off < 16; off <<= 1) ps += __shfl_xor(ps, off);
            float al = __expf(mo - mn);
            if (c4 == 0) { mrow[row] = mn; lrow[row] = lrow[row] * al + ps; arow[row] = al; }
            short tmp[8];
#pragma unroll
            for (int i = 0; i < 8; i++) tmp[i] = f2bf(v[i]);
            *(bf16x8*)&Pld[row * 136 + c4 * 8] = *(bf16x8*)tmp;
        }
        __syncthreads();   // Pld/arow ready; Sld reads done -> stage reusable
        // ---- rescale O, load P A-frags ----
        float al4[4];
#pragma unroll
        for (int r = 0; r < 4; r++) al4[r] = arow[wr * 16 + l4 * 4 + r];
#pragma unroll
        for (int t = 0; t < 8; t++)
#pragma unroll
            for (int r = 0; r < 4; r++) oacc[t][r] *= al4[r];
        bf16x8 pa[4];
#pragma unroll
        for (int kb = 0; kb < 4; kb++)
            pa[kb] = *(const bf16x8*)&Pld[(wr * 16 + l15) * 136 + kb * 32 + l4 * 8];
        // ---- O += P V, two e-halves staged ----
#pragma unroll
        for (int eh = 0; eh < 2; eh++) {
            if (eh) __syncthreads();   // eh0 covered by post-softmax sync
#pragma unroll
            for (int i = 0; i < 4; i++) {
                int vv = tid + i * 1024;
                int row = vv >> 4, col8 = (vv & 15) * 8;  // 256 x 128
                *(bf16x8*)&stage[row * 136 + col8] =
                    *(const bf16x8*)&vtb[(size_t)(eh * 256 + row) * NN + j0 + col8];
            }
            __syncthreads();
#pragma unroll
            for (int i = 0; i < 4; i++) {
#pragma unroll
                for (int kb = 0; kb < 4; kb++) {
                    bf16x8 vf = *(const bf16x8*)&stage[(wc * 64 + i * 16 + l15) * 136 + kb * 32 + l4 * 8];
                    oacc[eh * 4 + i] = mfma16(pa[kb], vf, oacc[eh * 4 + i]);
                }
            }
        }
    }
    __syncthreads();
    // ---- finalize: O /= l, store dpa (bf16) ----
    float li[4];
#pragma unroll
    for (int r = 0; r < 4; r++) li[r] = 1.f / lrow[wr * 16 + l4 * 4 + r];
    short* dpb = dpa + (size_t)b * (NN * ND);
#pragma unroll
    for (int eh = 0; eh < 2; eh++)
#pragma unroll
        for (int i = 0; i < 4; i++) {
            int col = eh * 256 + wc * 64 + i * 16 + l15;
#pragma unroll
            for (int r = 0; r < 4; r++) {
                int row = q0 + wr * 16 + l4 * 4 + r;
                dpb[(size_t)row * ND + col] = f2bf(oacc[eh * 4 + i][r] * li[r]);
            }
        }
}

extern "C" void kernel_launch(void* const* d_in, const int* in_sizes, int n_in,
                              void* d_out, int out_size, void* d_ws, size_t ws_size,
                              hipStream_t stream) {
    const float* q     = (const float*)d_in[0];
    const float* k     = (const float*)d_in[1];
    const float* v     = (const float*)d_in[2];
    const float* w_q   = (const float*)d_in[3];
    const float* w_k   = (const float*)d_in[4];
    const float* w_v   = (const float*)d_in[5];
    const float* w_mha = (const float*)d_in[6];
    const float* b_q   = (const float*)d_in[7];
    const float* b_k   = (const float*)d_in[8];
    const float* b_v   = (const float*)d_in[9];
    const float* b_mha = (const float*)d_in[10];

    const size_t T = (size_t)NB * NN * ND;  // 8388608
    short* ws  = (short*)d_ws;
    short* qp  = ws;
    short* kp  = qp + T;
    short* vpT = kp + T;
    short* dpa = vpT + T;
    short* Wt  = dpa + T;  // 4 * 262144 shorts

    Ptrs4 p;
    p.in[0] = w_q;   p.out[0] = Wt;
    p.in[1] = w_k;   p.out[1] = Wt + 262144;
    p.in[2] = w_v;   p.out[2] = Wt + 524288;
    p.in[3] = w_mha; p.out[3] = Wt + 786432;
    transpose_w<<<dim3(16, 16, 4), dim3(32, 8), 0, stream>>>(p);

    gemm_bt_bias<1, 0, 0><<<dim3(4, 128), 256, 0, stream>>>(q, Wt,          b_q, qp);
    gemm_bt_bias<1, 0, 0><<<dim3(4, 128), 256, 0, stream>>>(k, Wt + 262144, b_k, kp);
    gemm_bt_bias<1, 1, 0><<<dim3(4, 128), 256, 0, stream>>>(v, Wt + 524288, b_v, vpT);

    flash_attn<<<dim3(64, 4), 1024, 0, stream>>>(qp, kp, vpT, dpa);

    gemm_bt_bias<0, 0, 1><<<dim3(4, 128), 256, 0, stream>>>(dpa, Wt + 786432, b_mha, d_out);
}